// Round 1
// baseline (693.723 us; speedup 1.0000x reference)
//
#include <hip/hip_runtime.h>
#include <hip/hip_bf16.h>
#include <stdint.h>
#include <math.h>

#define S_LEN 2048
#define DMODEL 1024
#define NHEAD 16
#define DHEAD 64
#define FFDIM 4096
#define NLAYER 2

using bf16 = __hip_bfloat16;
typedef __attribute__((ext_vector_type(8))) short bf16x8;
typedef __attribute__((ext_vector_type(4))) float f32x4;

#define MFMA16x16(A, B, C) __builtin_amdgcn_mfma_f32_16x16x32_bf16(A, B, C, 0, 0, 0)

__device__ __forceinline__ float bf2f(uint32_t u16bits) {
  union { uint32_t i; float f; } x;
  x.i = u16bits << 16;
  return x.f;
}
__device__ __forceinline__ uint16_t f2bf(float f) {
  return __builtin_bit_cast(uint16_t, __float2bfloat16(f));
}

// ---------------------------------------------------------------------------
// Weight cast + transpose: in fp32 (R x C)  ->  out bf16 (C x R)
// ---------------------------------------------------------------------------
__global__ __launch_bounds__(256) void k_tcast(const float* __restrict__ in,
                                               bf16* __restrict__ out,
                                               int R, int C) {
  __shared__ float tl[32][33];
  int t = threadIdx.x;
  int r0 = blockIdx.y * 32, c0 = blockIdx.x * 32;
  int cl = t & 31, rl = t >> 5;  // rl in 0..7
#pragma unroll
  for (int i = 0; i < 4; ++i)
    tl[rl + i * 8][cl] = in[(size_t)(r0 + rl + i * 8) * C + c0 + cl];
  __syncthreads();
#pragma unroll
  for (int i = 0; i < 4; ++i)
    out[(size_t)(c0 + rl + i * 8) * R + r0 + cl] = __float2bfloat16(tl[cl][rl + i * 8]);
}

// ---------------------------------------------------------------------------
// LayerNorm over DMODEL=1024: 256 threads, 4 elems each. OUT = bf16 or float.
// ---------------------------------------------------------------------------
__device__ __forceinline__ void ln_store4(bf16* p, float a, float b, float c, float d) {
  uint2 u;
  u.x = (uint32_t)f2bf(a) | ((uint32_t)f2bf(b) << 16);
  u.y = (uint32_t)f2bf(c) | ((uint32_t)f2bf(d) << 16);
  *(uint2*)p = u;
}
__device__ __forceinline__ void ln_store4(float* p, float a, float b, float c, float d) {
  *(float4*)p = make_float4(a, b, c, d);
}

template <typename OUT>
__global__ __launch_bounds__(256) void k_ln(const float* __restrict__ h,
                                            const float* __restrict__ g,
                                            const float* __restrict__ b,
                                            OUT* __restrict__ y) {
  int row = blockIdx.x, t = threadIdx.x;
  const float4 v = ((const float4*)(h + (size_t)row * DMODEL))[t];
  float s = v.x + v.y + v.z + v.w;
  float s2 = v.x * v.x + v.y * v.y + v.z * v.z + v.w * v.w;
#pragma unroll
  for (int off = 32; off > 0; off >>= 1) {
    s += __shfl_down(s, off);
    s2 += __shfl_down(s2, off);
  }
  __shared__ float red[8];
  int w = t >> 6;
  if ((t & 63) == 0) { red[w] = s; red[4 + w] = s2; }
  __syncthreads();
  s = red[0] + red[1] + red[2] + red[3];
  s2 = red[4] + red[5] + red[6] + red[7];
  float mean = s * (1.0f / DMODEL);
  float var = s2 * (1.0f / DMODEL) - mean * mean;
  float rstd = rsqrtf(var + 1e-5f);
  float4 gv = ((const float4*)g)[t];
  float4 bv = ((const float4*)b)[t];
  float o0 = (v.x - mean) * rstd * gv.x + bv.x;
  float o1 = (v.y - mean) * rstd * gv.y + bv.y;
  float o2 = (v.z - mean) * rstd * gv.z + bv.z;
  float o3 = (v.w - mean) * rstd * gv.w + bv.w;
  ln_store4(y + (size_t)row * DMODEL + t * 4, o0, o1, o2, o3);
}

// ---------------------------------------------------------------------------
// RoPE on q,k sections of qkv (bf16), tables fp32 (S x 32). One thread per
// (s, h, pair). Writes contiguous q, k buffers.
// ---------------------------------------------------------------------------
__global__ __launch_bounds__(256) void k_rope(const bf16* __restrict__ qkv,
                                              const float* __restrict__ fcos,
                                              const float* __restrict__ fsin,
                                              bf16* __restrict__ qr,
                                              bf16* __restrict__ kr) {
  int idx = blockIdx.x * 256 + threadIdx.x;  // S*H*32 total
  int p = idx & 31;
  int hh = (idx >> 5) & (NHEAD - 1);
  int s = idx >> 9;
  float c = fcos[s * 32 + p], sn = fsin[s * 32 + p];
  int colq = hh * DHEAD + 2 * p;
  uint32_t rq = *(const uint32_t*)(qkv + (size_t)s * 3 * DMODEL + colq);
  uint32_t rk = *(const uint32_t*)(qkv + (size_t)s * 3 * DMODEL + DMODEL + colq);
  {
    float te = bf2f(rq & 0xffffu), to = bf2f(rq >> 16);
    uint32_t outv = (uint32_t)f2bf(te * c - to * sn) | ((uint32_t)f2bf(te * sn + to * c) << 16);
    *(uint32_t*)(qr + (size_t)s * DMODEL + colq) = outv;
  }
  {
    float te = bf2f(rk & 0xffffu), to = bf2f(rk >> 16);
    uint32_t outv = (uint32_t)f2bf(te * c - to * sn) | ((uint32_t)f2bf(te * sn + to * c) << 16);
    *(uint32_t*)(kr + (size_t)s * DMODEL + colq) = outv;
  }
}

// ---------------------------------------------------------------------------
// V transpose per head: vT[h][d][s] = qkv[s][2*DM + h*64 + d]
// ---------------------------------------------------------------------------
__global__ __launch_bounds__(256) void k_tv(const bf16* __restrict__ qkv,
                                            bf16* __restrict__ vT) {
  __shared__ bf16 tl[64][65];
  int t = threadIdx.x;
  int hh = blockIdx.y;
  int sb = blockIdx.x * 64;
#pragma unroll
  for (int i = 0; i < 16; ++i) {
    int e = i * 256 + t;
    int sl = e >> 6, d = e & 63;
    tl[sl][d] = qkv[(size_t)(sb + sl) * 3 * DMODEL + 2 * DMODEL + hh * DHEAD + d];
  }
  __syncthreads();
#pragma unroll
  for (int i = 0; i < 16; ++i) {
    int e = i * 256 + t;
    int d = e >> 6, sl = e & 63;
    vT[(size_t)(hh * DHEAD + d) * S_LEN + sb + sl] = tl[sl][d];
  }
}

// ---------------------------------------------------------------------------
// GEMM: C[M,N] = A[M,K](bf16) * BT[N,K](bf16)^T + bias[N], epilogue variants.
// EPI 0: store bf16.  EPI 1: out fp32 = res + acc + bias.  EPI 2: gelu -> bf16.
// 128x128 tile, BK=32, 4 waves each 64x64 (4x4 frags of 16x16x32).
// ---------------------------------------------------------------------------
template <int EPI>
__global__ __launch_bounds__(256) void k_gemm_bt(const bf16* __restrict__ A,
                                                 const bf16* __restrict__ BT,
                                                 const float* __restrict__ bias,
                                                 const float* __restrict__ res,
                                                 void* __restrict__ out,
                                                 int M, int N, int K) {
  __shared__ bf16 As[128 * 32];
  __shared__ bf16 Bs[128 * 32];
  int t = threadIdx.x;
  int w = t >> 6, l = t & 63, lr = l & 15, lg = l >> 4;
  int bm = blockIdx.x * 128, bn = blockIdx.y * 128;
  int wm = (w >> 1) * 64, wn = (w & 1) * 64;

  f32x4 zero4 = {0.f, 0.f, 0.f, 0.f};
  f32x4 acc[4][4];
#pragma unroll
  for (int mf = 0; mf < 4; ++mf)
#pragma unroll
    for (int nf = 0; nf < 4; ++nf) acc[mf][nf] = zero4;

  for (int kt = 0; kt < K; kt += 32) {
    __syncthreads();
#pragma unroll
    for (int i = 0; i < 2; ++i) {
      int chunk = i * 256 + t;
      int row = chunk >> 2, ko = (chunk & 3) * 8;
      __builtin_amdgcn_global_load_lds(
          (__attribute__((address_space(1))) void*)(A + (size_t)(bm + row) * K + kt + ko),
          (__attribute__((address_space(3))) void*)(As + chunk * 8), 16, 0, 0);
      __builtin_amdgcn_global_load_lds(
          (__attribute__((address_space(1))) void*)(BT + (size_t)(bn + row) * K + kt + ko),
          (__attribute__((address_space(3))) void*)(Bs + chunk * 8), 16, 0, 0);
    }
    __syncthreads();
    bf16x8 af[4], bfr[4];
#pragma unroll
    for (int mf = 0; mf < 4; ++mf)
      af[mf] = *(const bf16x8*)(As + (wm + mf * 16 + lr) * 32 + lg * 8);
#pragma unroll
    for (int nf = 0; nf < 4; ++nf)
      bfr[nf] = *(const bf16x8*)(Bs + (wn + nf * 16 + lr) * 32 + lg * 8);
#pragma unroll
    for (int mf = 0; mf < 4; ++mf)
#pragma unroll
      for (int nf = 0; nf < 4; ++nf)
        acc[mf][nf] = MFMA16x16(af[mf], bfr[nf], acc[mf][nf]);
  }

  float* outf = (float*)out;
  bf16* outb = (bf16*)out;
#pragma unroll
  for (int mf = 0; mf < 4; ++mf) {
#pragma unroll
    for (int nf = 0; nf < 4; ++nf) {
      int col = bn + wn + nf * 16 + lr;
      float bv = bias[col];
      int row0 = bm + wm + mf * 16 + lg * 4;
#pragma unroll
      for (int r = 0; r < 4; ++r) {
        float v = acc[mf][nf][r] + bv;
        size_t idx = (size_t)(row0 + r) * N + col;
        if (EPI == 0) {
          outb[idx] = __float2bfloat16(v);
        } else if (EPI == 1) {
          outf[idx] = res[idx] + v;
        } else {
          float gl = 0.5f * v * (1.0f + tanhf(0.7978845608028654f * (v + 0.044715f * v * v * v)));
          outb[idx] = __float2bfloat16(gl);
        }
      }
    }
  }
}

// ---------------------------------------------------------------------------
// Flash attention with segment bias (+1 for same segment), scale 1/8.
// Block: 4 waves, 64 q-rows of one head (16 rows/wave). Loop over 64-key tiles.
// ---------------------------------------------------------------------------
__global__ __launch_bounds__(256) void k_attn(const bf16* __restrict__ qr,
                                              const bf16* __restrict__ kr,
                                              const bf16* __restrict__ vT,
                                              const int* __restrict__ offs,
                                              bf16* __restrict__ ao) {
  __shared__ char segs[S_LEN];
  __shared__ bf16 sP[4][16][72];  // per-wave P scratch, padded (144B row stride)
  int t = threadIdx.x, w = t >> 6, l = t & 63, lr = l & 15, lg = l >> 4;
  int hh = blockIdx.y, qb = blockIdx.x * 64;

  int o0 = offs[0], o1 = offs[1], o2 = offs[2], o3 = offs[3], o4 = offs[4];
  for (int p = t; p < S_LEN; p += 256)
    segs[p] = (char)((o0 <= p) + (o1 <= p) + (o2 <= p) + (o3 <= p) + (o4 <= p));
  __syncthreads();

  int qrow = qb + w * 16;
  const bf16* qp = qr + (size_t)(qrow + lr) * DMODEL + hh * DHEAD + lg * 8;
  bf16x8 aq0 = *(const bf16x8*)(qp);
  bf16x8 aq1 = *(const bf16x8*)(qp + 32);

  f32x4 zero4 = {0.f, 0.f, 0.f, 0.f};
  f32x4 accO[4];
  float m_r[4], l_r[4];
  char segq[4];
#pragma unroll
  for (int r = 0; r < 4; ++r) {
    accO[r] = zero4;
    m_r[r] = -1e30f;
    l_r[r] = 0.f;
    segq[r] = segs[qrow + lg * 4 + r];
  }

  for (int jt = 0; jt < S_LEN / 64; ++jt) {
    int j0 = jt * 64;
    f32x4 accS[4];
#pragma unroll
    for (int jf = 0; jf < 4; ++jf) accS[jf] = zero4;
#pragma unroll
    for (int jf = 0; jf < 4; ++jf) {
      const bf16* kp = kr + (size_t)(j0 + jf * 16 + lr) * DMODEL + hh * DHEAD + lg * 8;
      bf16x8 b0 = *(const bf16x8*)(kp);
      bf16x8 b1 = *(const bf16x8*)(kp + 32);
      accS[jf] = MFMA16x16(aq0, b0, accS[jf]);
      accS[jf] = MFMA16x16(aq1, b1, accS[jf]);
    }
    // scale + segment bias
    char segj[4];
#pragma unroll
    for (int jf = 0; jf < 4; ++jf) segj[jf] = segs[j0 + jf * 16 + lr];
#pragma unroll
    for (int jf = 0; jf < 4; ++jf)
#pragma unroll
      for (int r = 0; r < 4; ++r)
        accS[jf][r] = accS[jf][r] * 0.125f + ((segq[r] == segj[jf]) ? 1.0f : 0.0f);
    // online softmax (rows live across the 16-lane column group)
    float rmax[4];
#pragma unroll
    for (int r = 0; r < 4; ++r)
      rmax[r] = fmaxf(fmaxf(accS[0][r], accS[1][r]), fmaxf(accS[2][r], accS[3][r]));
#pragma unroll
    for (int off = 1; off < 16; off <<= 1)
#pragma unroll
      for (int r = 0; r < 4; ++r) rmax[r] = fmaxf(rmax[r], __shfl_xor(rmax[r], off));

    float fs[4], psum[4];
#pragma unroll
    for (int r = 0; r < 4; ++r) {
      float mnew = fmaxf(m_r[r], rmax[r]);
      fs[r] = __expf(m_r[r] - mnew);
      m_r[r] = mnew;
      float ps = 0.f;
#pragma unroll
      for (int jf = 0; jf < 4; ++jf) {
        float pv = __expf(accS[jf][r] - mnew);
        accS[jf][r] = pv;
        ps += pv;
      }
      psum[r] = ps;
    }
#pragma unroll
    for (int off = 1; off < 16; off <<= 1)
#pragma unroll
      for (int r = 0; r < 4; ++r) psum[r] += __shfl_xor(psum[r], off);
#pragma unroll
    for (int r = 0; r < 4; ++r) l_r[r] = l_r[r] * fs[r] + psum[r];
#pragma unroll
    for (int df = 0; df < 4; ++df)
#pragma unroll
      for (int r = 0; r < 4; ++r) accO[df][r] *= fs[r];

    // P: C-layout -> A-layout via per-wave LDS scratch
#pragma unroll
    for (int jf = 0; jf < 4; ++jf)
#pragma unroll
      for (int r = 0; r < 4; ++r)
        sP[w][lg * 4 + r][jf * 16 + lr] = __float2bfloat16(accS[jf][r]);
    __syncthreads();
    bf16x8 pa0 = *(const bf16x8*)(&sP[w][lr][lg * 8]);
    bf16x8 pa1 = *(const bf16x8*)(&sP[w][lr][32 + lg * 8]);
#pragma unroll
    for (int df = 0; df < 4; ++df) {
      const bf16* vp = vT + (size_t)(hh * DHEAD + df * 16 + lr) * S_LEN + j0 + lg * 8;
      bf16x8 v0 = *(const bf16x8*)(vp);
      bf16x8 v1 = *(const bf16x8*)(vp + 32);
      accO[df] = MFMA16x16(pa0, v0, accO[df]);
      accO[df] = MFMA16x16(pa1, v1, accO[df]);
    }
    __syncthreads();
  }
#pragma unroll
  for (int df = 0; df < 4; ++df)
#pragma unroll
    for (int r = 0; r < 4; ++r) {
      float o = accO[df][r] / l_r[r];
      ao[(size_t)(qrow + lg * 4 + r) * DMODEL + hh * DHEAD + df * 16 + lr] = __float2bfloat16(o);
    }
}

// ---------------------------------------------------------------------------
extern "C" void kernel_launch(void* const* d_in, const int* in_sizes, int n_in,
                              void* d_out, int out_size, void* d_ws, size_t ws_size,
                              hipStream_t stream) {
  const float* x = (const float*)d_in[0];
  const int* offs = (const int*)d_in[1];
  const float* fcos = (const float*)d_in[2];
  const float* fsin = (const float*)d_in[3];
  const float* ln0g = (const float*)d_in[4];
  const float* ln0b = (const float*)d_in[5];
  const float* ln1g = (const float*)d_in[6];
  const float* ln1b = (const float*)d_in[7];
  const float* wqkv = (const float*)d_in[8];
  const float* bqkv = (const float*)d_in[9];
  const float* wo = (const float*)d_in[10];
  const float* bo = (const float*)d_in[11];
  const float* wu = (const float*)d_in[12];
  const float* bu = (const float*)d_in[13];
  const float* wd = (const float*)d_in[14];
  const float* bd = (const float*)d_in[15];
  const float* lnfg = (const float*)d_in[16];
  const float* lnfb = (const float*)d_in[17];

  char* ws = (char*)d_ws;
  size_t off = 0;
  auto alloc = [&](size_t bytes) -> void* {
    void* p = ws + off;
    off += (bytes + 255) & ~(size_t)255;
    return p;
  };
  bf16* wqkvT = (bf16*)alloc((size_t)NLAYER * 3 * DMODEL * DMODEL * 2);
  bf16* woT = (bf16*)alloc((size_t)NLAYER * DMODEL * DMODEL * 2);
  bf16* wuT = (bf16*)alloc((size_t)NLAYER * DMODEL * FFDIM * 2);
  bf16* wdT = (bf16*)alloc((size_t)NLAYER * FFDIM * DMODEL * 2);
  float* hbuf = (float*)alloc((size_t)S_LEN * DMODEL * 4);
  bf16* ybuf = (bf16*)alloc((size_t)S_LEN * DMODEL * 2);
  bf16* qkv = (bf16*)alloc((size_t)S_LEN * 3 * DMODEL * 2);
  bf16* qrb = (bf16*)alloc((size_t)S_LEN * DMODEL * 2);
  bf16* krb = (bf16*)alloc((size_t)S_LEN * DMODEL * 2);
  bf16* vTb = (bf16*)alloc((size_t)S_LEN * DMODEL * 2);
  bf16* aob = (bf16*)alloc((size_t)S_LEN * DMODEL * 2);
  bf16* midb = (bf16*)alloc((size_t)S_LEN * FFDIM * 2);

  for (int ly = 0; ly < NLAYER; ++ly) {
    k_tcast<<<dim3(3 * DMODEL / 32, DMODEL / 32), 256, 0, stream>>>(
        wqkv + (size_t)ly * DMODEL * 3 * DMODEL, wqkvT + (size_t)ly * 3 * DMODEL * DMODEL, DMODEL, 3 * DMODEL);
    k_tcast<<<dim3(DMODEL / 32, DMODEL / 32), 256, 0, stream>>>(
        wo + (size_t)ly * DMODEL * DMODEL, woT + (size_t)ly * DMODEL * DMODEL, DMODEL, DMODEL);
    k_tcast<<<dim3(FFDIM / 32, DMODEL / 32), 256, 0, stream>>>(
        wu + (size_t)ly * DMODEL * FFDIM, wuT + (size_t)ly * DMODEL * FFDIM, DMODEL, FFDIM);
    k_tcast<<<dim3(DMODEL / 32, FFDIM / 32), 256, 0, stream>>>(
        wd + (size_t)ly * FFDIM * DMODEL, wdT + (size_t)ly * FFDIM * DMODEL, FFDIM, DMODEL);
  }
  hipMemcpyAsync(hbuf, x, (size_t)S_LEN * DMODEL * 4, hipMemcpyDeviceToDevice, stream);

  for (int ly = 0; ly < NLAYER; ++ly) {
    k_ln<bf16><<<S_LEN, 256, 0, stream>>>(hbuf, ln0g + ly * DMODEL, ln0b + ly * DMODEL, ybuf);
    k_gemm_bt<0><<<dim3(S_LEN / 128, 3 * DMODEL / 128), 256, 0, stream>>>(
        ybuf, wqkvT + (size_t)ly * 3 * DMODEL * DMODEL, bqkv + ly * 3 * DMODEL, nullptr, qkv,
        S_LEN, 3 * DMODEL, DMODEL);
    k_rope<<<S_LEN * NHEAD * 32 / 256, 256, 0, stream>>>(qkv, fcos, fsin, qrb, krb);
    k_tv<<<dim3(S_LEN / 64, NHEAD), 256, 0, stream>>>(qkv, vTb);
    k_attn<<<dim3(S_LEN / 64, NHEAD), 256, 0, stream>>>(qrb, krb, vTb, offs, aob);
    k_gemm_bt<1><<<dim3(S_LEN / 128, DMODEL / 128), 256, 0, stream>>>(
        aob, woT + (size_t)ly * DMODEL * DMODEL, bo + ly * DMODEL, hbuf, hbuf,
        S_LEN, DMODEL, DMODEL);
    k_ln<bf16><<<S_LEN, 256, 0, stream>>>(hbuf, ln1g + ly * DMODEL, ln1b + ly * DMODEL, ybuf);
    k_gemm_bt<2><<<dim3(S_LEN / 128, FFDIM / 128), 256, 0, stream>>>(
        ybuf, wuT + (size_t)ly * DMODEL * FFDIM, bu + ly * FFDIM, nullptr, midb,
        S_LEN, FFDIM, DMODEL);
    k_gemm_bt<1><<<dim3(S_LEN / 128, DMODEL / 128), 256, 0, stream>>>(
        midb, wdT + (size_t)ly * FFDIM * DMODEL, bd + ly * DMODEL, hbuf, hbuf,
        S_LEN, DMODEL, FFDIM);
  }
  k_ln<float><<<S_LEN, 256, 0, stream>>>(hbuf, lnfg, lnfb, (float*)d_out);
}

// Round 2
// 663.831 us; speedup vs baseline: 1.0450x; 1.0450x over previous
//
#include <hip/hip_runtime.h>
#include <hip/hip_bf16.h>
#include <stdint.h>
#include <math.h>

#define S_LEN 2048
#define DMODEL 1024
#define NHEAD 16
#define DHEAD 64
#define FFDIM 4096
#define NLAYER 2

using bf16 = __hip_bfloat16;
typedef __attribute__((ext_vector_type(8))) short bf16x8;
typedef __attribute__((ext_vector_type(4))) float f32x4;

#define MFMA16x16(A, B, C) __builtin_amdgcn_mfma_f32_16x16x32_bf16(A, B, C, 0, 0, 0)

__device__ __forceinline__ float bf2f(uint32_t u16bits) {
  union { uint32_t i; float f; } x;
  x.i = u16bits << 16;
  return x.f;
}
__device__ __forceinline__ uint16_t f2bf(float f) {
  return __builtin_bit_cast(uint16_t, __float2bfloat16(f));
}

// ---------------------------------------------------------------------------
// Weight cast + transpose: in fp32 (R x C)  ->  out bf16 (C x R)
// ---------------------------------------------------------------------------
__global__ __launch_bounds__(256) void k_tcast(const float* __restrict__ in,
                                               bf16* __restrict__ out,
                                               int R, int C) {
  __shared__ float tl[32][33];
  int t = threadIdx.x;
  int r0 = blockIdx.y * 32, c0 = blockIdx.x * 32;
  int cl = t & 31, rl = t >> 5;  // rl in 0..7
#pragma unroll
  for (int i = 0; i < 4; ++i)
    tl[rl + i * 8][cl] = in[(size_t)(r0 + rl + i * 8) * C + c0 + cl];
  __syncthreads();
#pragma unroll
  for (int i = 0; i < 4; ++i)
    out[(size_t)(c0 + rl + i * 8) * R + r0 + cl] = __float2bfloat16(tl[cl][rl + i * 8]);
}

// ---------------------------------------------------------------------------
// LayerNorm over DMODEL=1024: 256 threads, 4 elems each. OUT = bf16 or float.
// ---------------------------------------------------------------------------
__device__ __forceinline__ void ln_store4(bf16* p, float a, float b, float c, float d) {
  uint2 u;
  u.x = (uint32_t)f2bf(a) | ((uint32_t)f2bf(b) << 16);
  u.y = (uint32_t)f2bf(c) | ((uint32_t)f2bf(d) << 16);
  *(uint2*)p = u;
}
__device__ __forceinline__ void ln_store4(float* p, float a, float b, float c, float d) {
  *(float4*)p = make_float4(a, b, c, d);
}

template <typename OUT>
__global__ __launch_bounds__(256) void k_ln(const float* __restrict__ h,
                                            const float* __restrict__ g,
                                            const float* __restrict__ b,
                                            OUT* __restrict__ y) {
  int row = blockIdx.x, t = threadIdx.x;
  const float4 v = ((const float4*)(h + (size_t)row * DMODEL))[t];
  float s = v.x + v.y + v.z + v.w;
  float s2 = v.x * v.x + v.y * v.y + v.z * v.z + v.w * v.w;
#pragma unroll
  for (int off = 32; off > 0; off >>= 1) {
    s += __shfl_down(s, off);
    s2 += __shfl_down(s2, off);
  }
  __shared__ float red[8];
  int w = t >> 6;
  if ((t & 63) == 0) { red[w] = s; red[4 + w] = s2; }
  __syncthreads();
  s = red[0] + red[1] + red[2] + red[3];
  s2 = red[4] + red[5] + red[6] + red[7];
  float mean = s * (1.0f / DMODEL);
  float var = s2 * (1.0f / DMODEL) - mean * mean;
  float rstd = rsqrtf(var + 1e-5f);
  float4 gv = ((const float4*)g)[t];
  float4 bv = ((const float4*)b)[t];
  float o0 = (v.x - mean) * rstd * gv.x + bv.x;
  float o1 = (v.y - mean) * rstd * gv.y + bv.y;
  float o2 = (v.z - mean) * rstd * gv.z + bv.z;
  float o3 = (v.w - mean) * rstd * gv.w + bv.w;
  ln_store4(y + (size_t)row * DMODEL + t * 4, o0, o1, o2, o3);
}

// ---------------------------------------------------------------------------
// RoPE on q,k sections of qkv (bf16), tables fp32 (S x 32). One thread per
// (s, h, pair). Writes contiguous q, k buffers.
// ---------------------------------------------------------------------------
__global__ __launch_bounds__(256) void k_rope(const bf16* __restrict__ qkv,
                                              const float* __restrict__ fcos,
                                              const float* __restrict__ fsin,
                                              bf16* __restrict__ qr,
                                              bf16* __restrict__ kr) {
  int idx = blockIdx.x * 256 + threadIdx.x;  // S*H*32 total
  int p = idx & 31;
  int hh = (idx >> 5) & (NHEAD - 1);
  int s = idx >> 9;
  float c = fcos[s * 32 + p], sn = fsin[s * 32 + p];
  int colq = hh * DHEAD + 2 * p;
  uint32_t rq = *(const uint32_t*)(qkv + (size_t)s * 3 * DMODEL + colq);
  uint32_t rk = *(const uint32_t*)(qkv + (size_t)s * 3 * DMODEL + DMODEL + colq);
  {
    float te = bf2f(rq & 0xffffu), to = bf2f(rq >> 16);
    uint32_t outv = (uint32_t)f2bf(te * c - to * sn) | ((uint32_t)f2bf(te * sn + to * c) << 16);
    *(uint32_t*)(qr + (size_t)s * DMODEL + colq) = outv;
  }
  {
    float te = bf2f(rk & 0xffffu), to = bf2f(rk >> 16);
    uint32_t outv = (uint32_t)f2bf(te * c - to * sn) | ((uint32_t)f2bf(te * sn + to * c) << 16);
    *(uint32_t*)(kr + (size_t)s * DMODEL + colq) = outv;
  }
}

// ---------------------------------------------------------------------------
// V transpose per head: vT[h][d][s] = qkv[s][2*DM + h*64 + d]
// ---------------------------------------------------------------------------
__global__ __launch_bounds__(256) void k_tv(const bf16* __restrict__ qkv,
                                            bf16* __restrict__ vT) {
  __shared__ bf16 tl[64][65];
  int t = threadIdx.x;
  int hh = blockIdx.y;
  int sb = blockIdx.x * 64;
#pragma unroll
  for (int i = 0; i < 16; ++i) {
    int e = i * 256 + t;
    int sl = e >> 6, d = e & 63;
    tl[sl][d] = qkv[(size_t)(sb + sl) * 3 * DMODEL + 2 * DMODEL + hh * DHEAD + d];
  }
  __syncthreads();
#pragma unroll
  for (int i = 0; i < 16; ++i) {
    int e = i * 256 + t;
    int d = e >> 6, sl = e & 63;
    vT[(size_t)(hh * DHEAD + d) * S_LEN + sb + sl] = tl[sl][d];
  }
}

// ---------------------------------------------------------------------------
// GEMM: C[M,N] = A[M,K](bf16) * BT[N,K](bf16)^T + bias[N], epilogue variants.
// EPI 0: store bf16.  EPI 1: out fp32 = res + acc + bias.  EPI 2: gelu -> bf16.
// 128x128 tile, BK=32, 4 waves each 64x64 (4x4 frags of 16x16x32).
// ---------------------------------------------------------------------------
template <int EPI>
__global__ __launch_bounds__(256) void k_gemm_bt(const bf16* __restrict__ A,
                                                 const bf16* __restrict__ BT,
                                                 const float* __restrict__ bias,
                                                 const float* __restrict__ res,
                                                 void* __restrict__ out,
                                                 int M, int N, int K) {
  __shared__ bf16 As[128 * 32];
  __shared__ bf16 Bs[128 * 32];
  int t = threadIdx.x;
  int w = t >> 6, l = t & 63, lr = l & 15, lg = l >> 4;
  int bm = blockIdx.x * 128, bn = blockIdx.y * 128;
  int wm = (w >> 1) * 64, wn = (w & 1) * 64;

  f32x4 zero4 = {0.f, 0.f, 0.f, 0.f};
  f32x4 acc[4][4];
#pragma unroll
  for (int mf = 0; mf < 4; ++mf)
#pragma unroll
    for (int nf = 0; nf < 4; ++nf) acc[mf][nf] = zero4;

  for (int kt = 0; kt < K; kt += 32) {
    __syncthreads();
#pragma unroll
    for (int i = 0; i < 2; ++i) {
      int chunk = i * 256 + t;
      int row = chunk >> 2, ko = (chunk & 3) * 8;
      __builtin_amdgcn_global_load_lds(
          (__attribute__((address_space(1))) void*)(A + (size_t)(bm + row) * K + kt + ko),
          (__attribute__((address_space(3))) void*)(As + chunk * 8), 16, 0, 0);
      __builtin_amdgcn_global_load_lds(
          (__attribute__((address_space(1))) void*)(BT + (size_t)(bn + row) * K + kt + ko),
          (__attribute__((address_space(3))) void*)(Bs + chunk * 8), 16, 0, 0);
    }
    __syncthreads();
    bf16x8 af[4], bfr[4];
#pragma unroll
    for (int mf = 0; mf < 4; ++mf)
      af[mf] = *(const bf16x8*)(As + (wm + mf * 16 + lr) * 32 + lg * 8);
#pragma unroll
    for (int nf = 0; nf < 4; ++nf)
      bfr[nf] = *(const bf16x8*)(Bs + (wn + nf * 16 + lr) * 32 + lg * 8);
#pragma unroll
    for (int mf = 0; mf < 4; ++mf)
#pragma unroll
      for (int nf = 0; nf < 4; ++nf)
        acc[mf][nf] = MFMA16x16(af[mf], bfr[nf], acc[mf][nf]);
  }

  float* outf = (float*)out;
  bf16* outb = (bf16*)out;
#pragma unroll
  for (int mf = 0; mf < 4; ++mf) {
#pragma unroll
    for (int nf = 0; nf < 4; ++nf) {
      int col = bn + wn + nf * 16 + lr;
      float bv = bias[col];
      int row0 = bm + wm + mf * 16 + lg * 4;
#pragma unroll
      for (int r = 0; r < 4; ++r) {
        float v = acc[mf][nf][r] + bv;
        size_t idx = (size_t)(row0 + r) * N + col;
        if (EPI == 0) {
          outb[idx] = __float2bfloat16(v);
        } else if (EPI == 1) {
          outf[idx] = res[idx] + v;
        } else {
          float gl = 0.5f * v * (1.0f + tanhf(0.7978845608028654f * (v + 0.044715f * v * v * v)));
          outb[idx] = __float2bfloat16(gl);
        }
      }
    }
  }
}

// ---------------------------------------------------------------------------
// Flash attention, split-K across waves. Block = 16 q-rows x 1 head, 4 waves
// each own a disjoint 512-key range (8 tiles of 64). No barriers in the main
// loop (sP is per-wave scratch; DS pipe is in-order per wave). Partial
// (m, l, O) merged across waves through LDS at the end.
// Grid: (NHEAD, S/16) so linear block id % 8 == head % 8 -> all blocks of one
// head land on one XCD; K/V working set per XCD = 2 heads = 1 MB << 4 MB L2.
// ---------------------------------------------------------------------------
__global__ __launch_bounds__(256, 4) void k_attn(const bf16* __restrict__ qr,
                                                 const bf16* __restrict__ kr,
                                                 const bf16* __restrict__ vT,
                                                 const int* __restrict__ offs,
                                                 bf16* __restrict__ ao) {
  __shared__ bf16 sP[4][16][72];    // per-wave P scratch (144B row stride)
  __shared__ float mM[4][16];
  __shared__ float lL[4][16];
  __shared__ float oO[4][16][68];   // padded: bank = (row*4 + d) % 32
  int t = threadIdx.x, w = t >> 6, l = t & 63, lr = l & 15, lg = l >> 4;
  int hh = blockIdx.x, qb = blockIdx.y * 16;

  int o0 = offs[0], o1 = offs[1], o2 = offs[2], o3 = offs[3], o4 = offs[4];
#define SEGF(p) ((o0 <= (p)) + (o1 <= (p)) + (o2 <= (p)) + (o3 <= (p)) + (o4 <= (p)))

  const bf16* qp = qr + (size_t)(qb + lr) * DMODEL + hh * DHEAD + lg * 8;
  bf16x8 aq0 = *(const bf16x8*)(qp);
  bf16x8 aq1 = *(const bf16x8*)(qp + 32);

  f32x4 zero4 = {0.f, 0.f, 0.f, 0.f};
  f32x4 accO[4];
  float m_r[4], l_r[4];
  int segq[4];
#pragma unroll
  for (int r = 0; r < 4; ++r) {
    accO[r] = zero4;
    m_r[r] = -1e30f;
    l_r[r] = 0.f;
    segq[r] = SEGF(qb + lg * 4 + r);
  }

  // this wave's disjoint key range: 8 tiles of 64
  for (int jt = w * 8; jt < w * 8 + 8; ++jt) {
    int j0 = jt * 64;
    f32x4 accS[4];
#pragma unroll
    for (int jf = 0; jf < 4; ++jf) accS[jf] = zero4;
#pragma unroll
    for (int jf = 0; jf < 4; ++jf) {
      const bf16* kp = kr + (size_t)(j0 + jf * 16 + lr) * DMODEL + hh * DHEAD + lg * 8;
      bf16x8 b0 = *(const bf16x8*)(kp);
      bf16x8 b1 = *(const bf16x8*)(kp + 32);
      accS[jf] = MFMA16x16(aq0, b0, accS[jf]);
      accS[jf] = MFMA16x16(aq1, b1, accS[jf]);
    }
    // scale + segment bias
#pragma unroll
    for (int jf = 0; jf < 4; ++jf) {
      int segj = SEGF(j0 + jf * 16 + lr);
#pragma unroll
      for (int r = 0; r < 4; ++r)
        accS[jf][r] = accS[jf][r] * 0.125f + ((segq[r] == segj) ? 1.0f : 0.0f);
    }
    // online softmax (rows live across the 16-lane column group)
    float rmax[4];
#pragma unroll
    for (int r = 0; r < 4; ++r)
      rmax[r] = fmaxf(fmaxf(accS[0][r], accS[1][r]), fmaxf(accS[2][r], accS[3][r]));
#pragma unroll
    for (int off = 1; off < 16; off <<= 1)
#pragma unroll
      for (int r = 0; r < 4; ++r) rmax[r] = fmaxf(rmax[r], __shfl_xor(rmax[r], off));

    float fs[4], psum[4];
#pragma unroll
    for (int r = 0; r < 4; ++r) {
      float mnew = fmaxf(m_r[r], rmax[r]);
      fs[r] = __expf(m_r[r] - mnew);
      m_r[r] = mnew;
      float ps = 0.f;
#pragma unroll
      for (int jf = 0; jf < 4; ++jf) {
        float pv = __expf(accS[jf][r] - mnew);
        accS[jf][r] = pv;
        ps += pv;
      }
      psum[r] = ps;
    }
#pragma unroll
    for (int off = 1; off < 16; off <<= 1)
#pragma unroll
      for (int r = 0; r < 4; ++r) psum[r] += __shfl_xor(psum[r], off);
#pragma unroll
    for (int r = 0; r < 4; ++r) l_r[r] = l_r[r] * fs[r] + psum[r];
#pragma unroll
    for (int df = 0; df < 4; ++df)
#pragma unroll
      for (int r = 0; r < 4; ++r) accO[df][r] *= fs[r];

    // P: C-layout -> A-layout via per-wave LDS scratch (wave-local ordering:
    // DS pipe is in-order per wave; fences stop compiler reordering).
#pragma unroll
    for (int jf = 0; jf < 4; ++jf)
#pragma unroll
      for (int r = 0; r < 4; ++r)
        sP[w][lg * 4 + r][jf * 16 + lr] = __float2bfloat16(accS[jf][r]);
    asm volatile("s_waitcnt lgkmcnt(0)" ::: "memory");
    bf16x8 pa0 = *(const bf16x8*)(&sP[w][lr][lg * 8]);
    bf16x8 pa1 = *(const bf16x8*)(&sP[w][lr][32 + lg * 8]);
#pragma unroll
    for (int df = 0; df < 4; ++df) {
      const bf16* vp = vT + (size_t)(hh * DHEAD + df * 16 + lr) * S_LEN + j0 + lg * 8;
      bf16x8 v0 = *(const bf16x8*)(vp);
      bf16x8 v1 = *(const bf16x8*)(vp + 32);
      accO[df] = MFMA16x16(pa0, v0, accO[df]);
      accO[df] = MFMA16x16(pa1, v1, accO[df]);
    }
    asm volatile("" ::: "memory");  // keep next iter's ds_writes below the reads
  }

  // publish partials
  if (lr == 0) {
#pragma unroll
    for (int r = 0; r < 4; ++r) {
      mM[w][lg * 4 + r] = m_r[r];
      lL[w][lg * 4 + r] = l_r[r];
    }
  }
#pragma unroll
  for (int df = 0; df < 4; ++df)
#pragma unroll
    for (int r = 0; r < 4; ++r)
      oO[w][lg * 4 + r][df * 16 + lr] = accO[df][r];
  __syncthreads();

  // merge: wave w handles d-block w (d = w*16 + lr), rows lg*4+r
#pragma unroll
  for (int r = 0; r < 4; ++r) {
    int row = lg * 4 + r;
    float m0 = mM[0][row], m1 = mM[1][row], m2 = mM[2][row], m3 = mM[3][row];
    float ms = fmaxf(fmaxf(m0, m1), fmaxf(m2, m3));
    float a0 = __expf(m0 - ms), a1 = __expf(m1 - ms);
    float a2 = __expf(m2 - ms), a3 = __expf(m3 - ms);
    float ll = a0 * lL[0][row] + a1 * lL[1][row] + a2 * lL[2][row] + a3 * lL[3][row];
    int d = w * 16 + lr;
    float oo = a0 * oO[0][row][d] + a1 * oO[1][row][d] + a2 * oO[2][row][d] + a3 * oO[3][row][d];
    ao[(size_t)(qb + row) * DMODEL + hh * DHEAD + d] = __float2bfloat16(oo / ll);
  }
#undef SEGF
}

// ---------------------------------------------------------------------------
extern "C" void kernel_launch(void* const* d_in, const int* in_sizes, int n_in,
                              void* d_out, int out_size, void* d_ws, size_t ws_size,
                              hipStream_t stream) {
  const float* x = (const float*)d_in[0];
  const int* offs = (const int*)d_in[1];
  const float* fcos = (const float*)d_in[2];
  const float* fsin = (const float*)d_in[3];
  const float* ln0g = (const float*)d_in[4];
  const float* ln0b = (const float*)d_in[5];
  const float* ln1g = (const float*)d_in[6];
  const float* ln1b = (const float*)d_in[7];
  const float* wqkv = (const float*)d_in[8];
  const float* bqkv = (const float*)d_in[9];
  const float* wo = (const float*)d_in[10];
  const float* bo = (const float*)d_in[11];
  const float* wu = (const float*)d_in[12];
  const float* bu = (const float*)d_in[13];
  const float* wd = (const float*)d_in[14];
  const float* bd = (const float*)d_in[15];
  const float* lnfg = (const float*)d_in[16];
  const float* lnfb = (const float*)d_in[17];

  char* ws = (char*)d_ws;
  size_t off = 0;
  auto alloc = [&](size_t bytes) -> void* {
    void* p = ws + off;
    off += (bytes + 255) & ~(size_t)255;
    return p;
  };
  bf16* wqkvT = (bf16*)alloc((size_t)NLAYER * 3 * DMODEL * DMODEL * 2);
  bf16* woT = (bf16*)alloc((size_t)NLAYER * DMODEL * DMODEL * 2);
  bf16* wuT = (bf16*)alloc((size_t)NLAYER * DMODEL * FFDIM * 2);
  bf16* wdT = (bf16*)alloc((size_t)NLAYER * FFDIM * DMODEL * 2);
  float* hbuf = (float*)alloc((size_t)S_LEN * DMODEL * 4);
  bf16* ybuf = (bf16*)alloc((size_t)S_LEN * DMODEL * 2);
  bf16* qkv = (bf16*)alloc((size_t)S_LEN * 3 * DMODEL * 2);
  bf16* qrb = (bf16*)alloc((size_t)S_LEN * DMODEL * 2);
  bf16* krb = (bf16*)alloc((size_t)S_LEN * DMODEL * 2);
  bf16* vTb = (bf16*)alloc((size_t)S_LEN * DMODEL * 2);
  bf16* aob = (bf16*)alloc((size_t)S_LEN * DMODEL * 2);
  bf16* midb = (bf16*)alloc((size_t)S_LEN * FFDIM * 2);

  for (int ly = 0; ly < NLAYER; ++ly) {
    k_tcast<<<dim3(3 * DMODEL / 32, DMODEL / 32), 256, 0, stream>>>(
        wqkv + (size_t)ly * DMODEL * 3 * DMODEL, wqkvT + (size_t)ly * 3 * DMODEL * DMODEL, DMODEL, 3 * DMODEL);
    k_tcast<<<dim3(DMODEL / 32, DMODEL / 32), 256, 0, stream>>>(
        wo + (size_t)ly * DMODEL * DMODEL, woT + (size_t)ly * DMODEL * DMODEL, DMODEL, DMODEL);
    k_tcast<<<dim3(FFDIM / 32, DMODEL / 32), 256, 0, stream>>>(
        wu + (size_t)ly * DMODEL * FFDIM, wuT + (size_t)ly * DMODEL * FFDIM, DMODEL, FFDIM);
    k_tcast<<<dim3(DMODEL / 32, FFDIM / 32), 256, 0, stream>>>(
        wd + (size_t)ly * FFDIM * DMODEL, wdT + (size_t)ly * FFDIM * DMODEL, FFDIM, DMODEL);
  }
  hipMemcpyAsync(hbuf, x, (size_t)S_LEN * DMODEL * 4, hipMemcpyDeviceToDevice, stream);

  for (int ly = 0; ly < NLAYER; ++ly) {
    k_ln<bf16><<<S_LEN, 256, 0, stream>>>(hbuf, ln0g + ly * DMODEL, ln0b + ly * DMODEL, ybuf);
    k_gemm_bt<0><<<dim3(S_LEN / 128, 3 * DMODEL / 128), 256, 0, stream>>>(
        ybuf, wqkvT + (size_t)ly * 3 * DMODEL * DMODEL, bqkv + ly * 3 * DMODEL, nullptr, qkv,
        S_LEN, 3 * DMODEL, DMODEL);
    k_rope<<<S_LEN * NHEAD * 32 / 256, 256, 0, stream>>>(qkv, fcos, fsin, qrb, krb);
    k_tv<<<dim3(S_LEN / 64, NHEAD), 256, 0, stream>>>(qkv, vTb);
    k_attn<<<dim3(NHEAD, S_LEN / 16), 256, 0, stream>>>(qrb, krb, vTb, offs, aob);
    k_gemm_bt<1><<<dim3(S_LEN / 128, DMODEL / 128), 256, 0, stream>>>(
        aob, woT + (size_t)ly * DMODEL * DMODEL, bo + ly * DMODEL, hbuf, hbuf,
        S_LEN, DMODEL, DMODEL);
    k_ln<bf16><<<S_LEN, 256, 0, stream>>>(hbuf, ln1g + ly * DMODEL, ln1b + ly * DMODEL, ybuf);
    k_gemm_bt<2><<<dim3(S_LEN / 128, FFDIM / 128), 256, 0, stream>>>(
        ybuf, wuT + (size_t)ly * DMODEL * FFDIM, bu + ly * FFDIM, nullptr, midb,
        S_LEN, FFDIM, DMODEL);
    k_gemm_bt<1><<<dim3(S_LEN / 128, DMODEL / 128), 256, 0, stream>>>(
        midb, wdT + (size_t)ly * FFDIM * DMODEL, bd + ly * DMODEL, hbuf, hbuf,
        S_LEN, DMODEL, FFDIM);
  }
  k_ln<float><<<S_LEN, 256, 0, stream>>>(hbuf, lnfg, lnfb, (float*)d_out);
}

// Round 3
// 639.744 us; speedup vs baseline: 1.0844x; 1.0377x over previous
//
#include <hip/hip_runtime.h>
#include <hip/hip_bf16.h>
#include <stdint.h>
#include <math.h>

#define S_LEN 2048
#define DMODEL 1024
#define NHEAD 16
#define DHEAD 64
#define FFDIM 4096
#define NLAYER 2

using bf16 = __hip_bfloat16;
typedef __attribute__((ext_vector_type(8))) short bf16x8;
typedef __attribute__((ext_vector_type(4))) float f32x4;

#define MFMA16x16(A, B, C) __builtin_amdgcn_mfma_f32_16x16x32_bf16(A, B, C, 0, 0, 0)
#define EXP2(x) __builtin_amdgcn_exp2f(x)

__device__ __forceinline__ float bf2f(uint32_t u16bits) {
  union { uint32_t i; float f; } x;
  x.i = u16bits << 16;
  return x.f;
}
__device__ __forceinline__ uint16_t f2bf(float f) {
  return __builtin_bit_cast(uint16_t, __float2bfloat16(f));
}

// DPP 16-lane (row) reductions — VALU pipe, no LDS traffic.
template <int CTRL>
__device__ __forceinline__ float dppf(float x) {
  return __builtin_bit_cast(float,
      __builtin_amdgcn_update_dpp(0, __builtin_bit_cast(int, x), CTRL, 0xF, 0xF, true));
}
__device__ __forceinline__ float rowmax16(float x) {
  x = fmaxf(x, dppf<0xB1>(x));   // quad_perm xor1
  x = fmaxf(x, dppf<0x4E>(x));   // quad_perm xor2
  x = fmaxf(x, dppf<0x141>(x));  // row_half_mirror
  x = fmaxf(x, dppf<0x140>(x));  // row_mirror
  return x;
}
__device__ __forceinline__ float rowsum16(float x) {
  x += dppf<0xB1>(x);
  x += dppf<0x4E>(x);
  x += dppf<0x141>(x);
  x += dppf<0x140>(x);
  return x;
}

// ---------------------------------------------------------------------------
// Weight cast + transpose: in fp32 (R x C)  ->  out bf16 (C x R)
// ---------------------------------------------------------------------------
__global__ __launch_bounds__(256) void k_tcast(const float* __restrict__ in,
                                               bf16* __restrict__ out,
                                               int R, int C) {
  __shared__ float tl[32][33];
  int t = threadIdx.x;
  int r0 = blockIdx.y * 32, c0 = blockIdx.x * 32;
  int cl = t & 31, rl = t >> 5;
#pragma unroll
  for (int i = 0; i < 4; ++i)
    tl[rl + i * 8][cl] = in[(size_t)(r0 + rl + i * 8) * C + c0 + cl];
  __syncthreads();
#pragma unroll
  for (int i = 0; i < 4; ++i)
    out[(size_t)(c0 + rl + i * 8) * R + r0 + cl] = __float2bfloat16(tl[cl][rl + i * 8]);
}

// ---------------------------------------------------------------------------
// LayerNorm over DMODEL=1024
// ---------------------------------------------------------------------------
__device__ __forceinline__ void ln_store4(bf16* p, float a, float b, float c, float d) {
  uint2 u;
  u.x = (uint32_t)f2bf(a) | ((uint32_t)f2bf(b) << 16);
  u.y = (uint32_t)f2bf(c) | ((uint32_t)f2bf(d) << 16);
  *(uint2*)p = u;
}
__device__ __forceinline__ void ln_store4(float* p, float a, float b, float c, float d) {
  *(float4*)p = make_float4(a, b, c, d);
}

template <typename OUT>
__global__ __launch_bounds__(256) void k_ln(const float* __restrict__ h,
                                            const float* __restrict__ g,
                                            const float* __restrict__ b,
                                            OUT* __restrict__ y) {
  int row = blockIdx.x, t = threadIdx.x;
  const float4 v = ((const float4*)(h + (size_t)row * DMODEL))[t];
  float s = v.x + v.y + v.z + v.w;
  float s2 = v.x * v.x + v.y * v.y + v.z * v.z + v.w * v.w;
#pragma unroll
  for (int off = 32; off > 0; off >>= 1) {
    s += __shfl_down(s, off);
    s2 += __shfl_down(s2, off);
  }
  __shared__ float red[8];
  int w = t >> 6;
  if ((t & 63) == 0) { red[w] = s; red[4 + w] = s2; }
  __syncthreads();
  s = red[0] + red[1] + red[2] + red[3];
  s2 = red[4] + red[5] + red[6] + red[7];
  float mean = s * (1.0f / DMODEL);
  float var = s2 * (1.0f / DMODEL) - mean * mean;
  float rstd = rsqrtf(var + 1e-5f);
  float4 gv = ((const float4*)g)[t];
  float4 bv = ((const float4*)b)[t];
  float o0 = (v.x - mean) * rstd * gv.x + bv.x;
  float o1 = (v.y - mean) * rstd * gv.y + bv.y;
  float o2 = (v.z - mean) * rstd * gv.z + bv.z;
  float o3 = (v.w - mean) * rstd * gv.w + bv.w;
  ln_store4(y + (size_t)row * DMODEL + t * 4, o0, o1, o2, o3);
}

// ---------------------------------------------------------------------------
// RoPE on q,k sections of qkv
// ---------------------------------------------------------------------------
__global__ __launch_bounds__(256) void k_rope(const bf16* __restrict__ qkv,
                                              const float* __restrict__ fcos,
                                              const float* __restrict__ fsin,
                                              bf16* __restrict__ qr,
                                              bf16* __restrict__ kr) {
  int idx = blockIdx.x * 256 + threadIdx.x;
  int p = idx & 31;
  int hh = (idx >> 5) & (NHEAD - 1);
  int s = idx >> 9;
  float c = fcos[s * 32 + p], sn = fsin[s * 32 + p];
  int colq = hh * DHEAD + 2 * p;
  uint32_t rq = *(const uint32_t*)(qkv + (size_t)s * 3 * DMODEL + colq);
  uint32_t rk = *(const uint32_t*)(qkv + (size_t)s * 3 * DMODEL + DMODEL + colq);
  {
    float te = bf2f(rq & 0xffffu), to = bf2f(rq >> 16);
    uint32_t outv = (uint32_t)f2bf(te * c - to * sn) | ((uint32_t)f2bf(te * sn + to * c) << 16);
    *(uint32_t*)(qr + (size_t)s * DMODEL + colq) = outv;
  }
  {
    float te = bf2f(rk & 0xffffu), to = bf2f(rk >> 16);
    uint32_t outv = (uint32_t)f2bf(te * c - to * sn) | ((uint32_t)f2bf(te * sn + to * c) << 16);
    *(uint32_t*)(kr + (size_t)s * DMODEL + colq) = outv;
  }
}

// ---------------------------------------------------------------------------
// V transpose per head: vT[h][d][s]
// ---------------------------------------------------------------------------
__global__ __launch_bounds__(256) void k_tv(const bf16* __restrict__ qkv,
                                            bf16* __restrict__ vT) {
  __shared__ bf16 tl[64][65];
  int t = threadIdx.x;
  int hh = blockIdx.y;
  int sb = blockIdx.x * 64;
#pragma unroll
  for (int i = 0; i < 16; ++i) {
    int e = i * 256 + t;
    int sl = e >> 6, d = e & 63;
    tl[sl][d] = qkv[(size_t)(sb + sl) * 3 * DMODEL + 2 * DMODEL + hh * DHEAD + d];
  }
  __syncthreads();
#pragma unroll
  for (int i = 0; i < 16; ++i) {
    int e = i * 256 + t;
    int d = e >> 6, sl = e & 63;
    vT[(size_t)(hh * DHEAD + d) * S_LEN + sb + sl] = tl[sl][d];
  }
}

// ---------------------------------------------------------------------------
// GEMM: C[M,N] = A[M,K](bf16) * BT[N,K]^T + bias[N].
// EPI 0: bf16.  EPI 1: fp32 = res + acc + bias.  EPI 2: gelu -> bf16.
// BM x 128 tile, BK=32. BM=128: 4 waves x (64x64). BM=64: 4 waves x (32x64)
// (grid doubles -> fixes half-idle GPU on N=1024 GEMMs).
// ---------------------------------------------------------------------------
template <int EPI, int BM>
__global__ __launch_bounds__(256) void k_gemm_bt(const bf16* __restrict__ A,
                                                 const bf16* __restrict__ BT,
                                                 const float* __restrict__ bias,
                                                 const float* __restrict__ res,
                                                 void* __restrict__ out,
                                                 int M, int N, int K) {
  constexpr int MF = BM / 32;  // m-frags per wave
  __shared__ bf16 As[BM * 32];
  __shared__ bf16 Bs[128 * 32];
  int t = threadIdx.x;
  int w = t >> 6, l = t & 63, lr = l & 15, lg = l >> 4;
  int bm = blockIdx.x * BM, bn = blockIdx.y * 128;
  int wm = (w >> 1) * (BM / 2), wn = (w & 1) * 64;

  f32x4 zero4 = {0.f, 0.f, 0.f, 0.f};
  f32x4 acc[MF][4];
#pragma unroll
  for (int mf = 0; mf < MF; ++mf)
#pragma unroll
    for (int nf = 0; nf < 4; ++nf) acc[mf][nf] = zero4;

  for (int kt = 0; kt < K; kt += 32) {
    __syncthreads();
#pragma unroll
    for (int i = 0; i < BM / 64; ++i) {
      int chunk = i * 256 + t;
      int row = chunk >> 2, ko = (chunk & 3) * 8;
      __builtin_amdgcn_global_load_lds(
          (__attribute__((address_space(1))) void*)(A + (size_t)(bm + row) * K + kt + ko),
          (__attribute__((address_space(3))) void*)(As + chunk * 8), 16, 0, 0);
    }
#pragma unroll
    for (int i = 0; i < 2; ++i) {
      int chunk = i * 256 + t;
      int row = chunk >> 2, ko = (chunk & 3) * 8;
      __builtin_amdgcn_global_load_lds(
          (__attribute__((address_space(1))) void*)(BT + (size_t)(bn + row) * K + kt + ko),
          (__attribute__((address_space(3))) void*)(Bs + chunk * 8), 16, 0, 0);
    }
    __syncthreads();
    bf16x8 af[MF], bfr[4];
#pragma unroll
    for (int mf = 0; mf < MF; ++mf)
      af[mf] = *(const bf16x8*)(As + (wm + mf * 16 + lr) * 32 + lg * 8);
#pragma unroll
    for (int nf = 0; nf < 4; ++nf)
      bfr[nf] = *(const bf16x8*)(Bs + (wn + nf * 16 + lr) * 32 + lg * 8);
#pragma unroll
    for (int mf = 0; mf < MF; ++mf)
#pragma unroll
      for (int nf = 0; nf < 4; ++nf)
        acc[mf][nf] = MFMA16x16(af[mf], bfr[nf], acc[mf][nf]);
  }

  float* outf = (float*)out;
  bf16* outb = (bf16*)out;
#pragma unroll
  for (int mf = 0; mf < MF; ++mf) {
#pragma unroll
    for (int nf = 0; nf < 4; ++nf) {
      int col = bn + wn + nf * 16 + lr;
      float bv = bias[col];
      int row0 = bm + wm + mf * 16 + lg * 4;
#pragma unroll
      for (int r = 0; r < 4; ++r) {
        float v = acc[mf][nf][r] + bv;
        size_t idx = (size_t)(row0 + r) * N + col;
        if (EPI == 0) {
          outb[idx] = __float2bfloat16(v);
        } else if (EPI == 1) {
          outf[idx] = res[idx] + v;
        } else {
          float gl = 0.5f * v * (1.0f + tanhf(0.7978845608028654f * (v + 0.044715f * v * v * v)));
          outb[idx] = __float2bfloat16(gl);
        }
      }
    }
  }
}

// ---------------------------------------------------------------------------
// Flash attention v3. Split-K across 4 waves (512 keys each), KVBLK=128,
// softmax in exp2 domain, DPP row-reduce (no LDS shuffles), defer-max,
// XOR-swizzled per-wave P scratch, V prefetch, setprio around MFMA.
// Grid (NHEAD, S/16): block id % 8 == head % 8 -> per-XCD K/V L2 locality.
// ---------------------------------------------------------------------------
__global__ __launch_bounds__(256, 4) void k_attn(const bf16* __restrict__ qr,
                                                 const bf16* __restrict__ kr,
                                                 const bf16* __restrict__ vT,
                                                 const int* __restrict__ offs,
                                                 bf16* __restrict__ ao) {
  __shared__ char segs[S_LEN];
  __shared__ bf16 sP[4 * 16 * 128];  // per-wave [16][128], col ^= (row&3)<<4
  __shared__ float mM[4][16];
  __shared__ float lL[4][16];
  __shared__ float oO[4][16][68];
  int t = threadIdx.x, w = t >> 6, l = t & 63, lr = l & 15, lg = l >> 4;
  int hh = blockIdx.x, qb = blockIdx.y * 16;

  int o0 = offs[0], o1 = offs[1], o2 = offs[2], o3 = offs[3], o4 = offs[4];
  for (int p = t; p < S_LEN; p += 256)
    segs[p] = (char)((o0 <= p) + (o1 <= p) + (o2 <= p) + (o3 <= p) + (o4 <= p));
  __syncthreads();

  constexpr float LOG2E = 1.4426950408889634f;
  constexpr float C1 = 0.125f * LOG2E;

  const bf16* qp = qr + (size_t)(qb + lr) * DMODEL + hh * DHEAD + lg * 8;
  bf16x8 aq0 = *(const bf16x8*)(qp);
  bf16x8 aq1 = *(const bf16x8*)(qp + 32);

  bf16* sPw = sP + w * 2048;
  const bf16* vTh = vT + (size_t)hh * DHEAD * S_LEN;

  f32x4 zero4 = {0.f, 0.f, 0.f, 0.f};
  f32x4 accO[4];
  float m_r[4], l_p[4];
  int segq[4];
#pragma unroll
  for (int r = 0; r < 4; ++r) {
    accO[r] = zero4;
    m_r[r] = -1e30f;
    l_p[r] = 0.f;
    segq[r] = segs[qb + lg * 4 + r];
  }

  for (int it = 0; it < 4; ++it) {
    int j0 = w * 512 + it * 128;
    // ---- QK^T over 128 keys, two reg-batches of 4 key-frags ----
    f32x4 accS[8];
#pragma unroll
    for (int half = 0; half < 2; ++half) {
      bf16x8 kb0[4], kb1[4];
#pragma unroll
      for (int j = 0; j < 4; ++j) {
        int jf = half * 4 + j;
        const bf16* kp = kr + (size_t)(j0 + jf * 16 + lr) * DMODEL + hh * DHEAD + lg * 8;
        kb0[j] = *(const bf16x8*)(kp);
        kb1[j] = *(const bf16x8*)(kp + 32);
      }
      __builtin_amdgcn_s_setprio(1);
#pragma unroll
      for (int j = 0; j < 4; ++j) {
        accS[half * 4 + j] = MFMA16x16(aq0, kb0[j], zero4);
        accS[half * 4 + j] = MFMA16x16(aq1, kb1[j], accS[half * 4 + j]);
      }
      __builtin_amdgcn_s_setprio(0);
    }
    // ---- V prefetch (df=0) overlaps softmax ----
    bf16x8 v0[4];
#pragma unroll
    for (int ks = 0; ks < 4; ++ks)
      v0[ks] = *(const bf16x8*)(vTh + (size_t)lr * S_LEN + j0 + ks * 32 + lg * 8);
    // ---- scale + segment bias (exp2 domain) ----
    int sj[8];
#pragma unroll
    for (int jf = 0; jf < 8; ++jf) sj[jf] = segs[j0 + jf * 16 + lr];
#pragma unroll
    for (int jf = 0; jf < 8; ++jf)
#pragma unroll
      for (int r = 0; r < 4; ++r)
        accS[jf][r] = accS[jf][r] * C1 + ((segq[r] == sj[jf]) ? LOG2E : 0.0f);
    // ---- row max: 7 in-reg + 4 DPP steps ----
    float rmax[4];
#pragma unroll
    for (int r = 0; r < 4; ++r) {
      float a = fmaxf(fmaxf(accS[0][r], accS[1][r]), fmaxf(accS[2][r], accS[3][r]));
      float b = fmaxf(fmaxf(accS[4][r], accS[5][r]), fmaxf(accS[6][r], accS[7][r]));
      rmax[r] = rowmax16(fmaxf(a, b));
    }
    // ---- defer-max: rescale only when max grows by > 8 (log2) ----
    int need = 0;
#pragma unroll
    for (int r = 0; r < 4; ++r) need |= (rmax[r] > m_r[r] + 8.0f) ? 1 : 0;
    if (__any(need)) {
#pragma unroll
      for (int r = 0; r < 4; ++r) {
        float mnew = fmaxf(m_r[r], rmax[r]);
        float fs = EXP2(m_r[r] - mnew);
        m_r[r] = mnew;
        l_p[r] *= fs;
#pragma unroll
        for (int df = 0; df < 4; ++df) accO[df][r] *= fs;
      }
    }
    // ---- exp2 + P write (swizzled; row&3 == r, so offsets fold to imm) ----
#pragma unroll
    for (int jf = 0; jf < 8; ++jf)
#pragma unroll
      for (int r = 0; r < 4; ++r) {
        float pv = EXP2(accS[jf][r] - m_r[r]);
        l_p[r] += pv;
        sPw[(lg * 4 + r) * 128 + ((jf ^ r) * 16) + lr] = __float2bfloat16(pv);
      }
    asm volatile("s_waitcnt lgkmcnt(0)" ::: "memory");
    bf16x8 pa[4];
#pragma unroll
    for (int ks = 0; ks < 4; ++ks)
      pa[ks] = *(const bf16x8*)(sPw + lr * 128 + (((ks * 32 + lg * 8) ^ ((lr & 3) << 4))));
    // ---- remaining V loads, then PV MFMAs ----
    bf16x8 v123[3][4];
#pragma unroll
    for (int df = 1; df < 4; ++df)
#pragma unroll
      for (int ks = 0; ks < 4; ++ks)
        v123[df - 1][ks] =
            *(const bf16x8*)(vTh + (size_t)(df * 16 + lr) * S_LEN + j0 + ks * 32 + lg * 8);
    __builtin_amdgcn_s_setprio(1);
#pragma unroll
    for (int ks = 0; ks < 4; ++ks) accO[0] = MFMA16x16(pa[ks], v0[ks], accO[0]);
#pragma unroll
    for (int df = 1; df < 4; ++df)
#pragma unroll
      for (int ks = 0; ks < 4; ++ks)
        accO[df] = MFMA16x16(pa[ks], v123[df - 1][ks], accO[df]);
    __builtin_amdgcn_s_setprio(0);
    asm volatile("" ::: "memory");  // keep next iter's ds_writes after reads
  }

  // finalize l (per-lane partials -> row totals), publish partials
#pragma unroll
  for (int r = 0; r < 4; ++r) l_p[r] = rowsum16(l_p[r]);
  if (lr == 0) {
#pragma unroll
    for (int r = 0; r < 4; ++r) {
      mM[w][lg * 4 + r] = m_r[r];
      lL[w][lg * 4 + r] = l_p[r];
    }
  }
#pragma unroll
  for (int df = 0; df < 4; ++df)
#pragma unroll
    for (int r = 0; r < 4; ++r)
      oO[w][lg * 4 + r][df * 16 + lr] = accO[df][r];
  __syncthreads();

  // merge across waves: wave w handles d = w*16 + lr, rows lg*4+r
#pragma unroll
  for (int r = 0; r < 4; ++r) {
    int row = lg * 4 + r;
    float m0 = mM[0][row], m1 = mM[1][row], m2 = mM[2][row], m3 = mM[3][row];
    float ms = fmaxf(fmaxf(m0, m1), fmaxf(m2, m3));
    float a0 = EXP2(m0 - ms), a1 = EXP2(m1 - ms);
    float a2 = EXP2(m2 - ms), a3 = EXP2(m3 - ms);
    float ll = a0 * lL[0][row] + a1 * lL[1][row] + a2 * lL[2][row] + a3 * lL[3][row];
    int d = w * 16 + lr;
    float oo = a0 * oO[0][row][d] + a1 * oO[1][row][d] + a2 * oO[2][row][d] + a3 * oO[3][row][d];
    ao[(size_t)(qb + row) * DMODEL + hh * DHEAD + d] = __float2bfloat16(oo / ll);
  }
}

// ---------------------------------------------------------------------------
extern "C" void kernel_launch(void* const* d_in, const int* in_sizes, int n_in,
                              void* d_out, int out_size, void* d_ws, size_t ws_size,
                              hipStream_t stream) {
  const float* x = (const float*)d_in[0];
  const int* offs = (const int*)d_in[1];
  const float* fcos = (const float*)d_in[2];
  const float* fsin = (const float*)d_in[3];
  const float* ln0g = (const float*)d_in[4];
  const float* ln0b = (const float*)d_in[5];
  const float* ln1g = (const float*)d_in[6];
  const float* ln1b = (const float*)d_in[7];
  const float* wqkv = (const float*)d_in[8];
  const float* bqkv = (const float*)d_in[9];
  const float* wo = (const float*)d_in[10];
  const float* bo = (const float*)d_in[11];
  const float* wu = (const float*)d_in[12];
  const float* bu = (const float*)d_in[13];
  const float* wd = (const float*)d_in[14];
  const float* bd = (const float*)d_in[15];
  const float* lnfg = (const float*)d_in[16];
  const float* lnfb = (const float*)d_in[17];

  char* ws = (char*)d_ws;
  size_t off = 0;
  auto alloc = [&](size_t bytes) -> void* {
    void* p = ws + off;
    off += (bytes + 255) & ~(size_t)255;
    return p;
  };
  bf16* wqkvT = (bf16*)alloc((size_t)NLAYER * 3 * DMODEL * DMODEL * 2);
  bf16* woT = (bf16*)alloc((size_t)NLAYER * DMODEL * DMODEL * 2);
  bf16* wuT = (bf16*)alloc((size_t)NLAYER * DMODEL * FFDIM * 2);
  bf16* wdT = (bf16*)alloc((size_t)NLAYER * FFDIM * DMODEL * 2);
  float* hbuf = (float*)alloc((size_t)S_LEN * DMODEL * 4);
  bf16* ybuf = (bf16*)alloc((size_t)S_LEN * DMODEL * 2);
  bf16* qkv = (bf16*)alloc((size_t)S_LEN * 3 * DMODEL * 2);
  bf16* qrb = (bf16*)alloc((size_t)S_LEN * DMODEL * 2);
  bf16* krb = (bf16*)alloc((size_t)S_LEN * DMODEL * 2);
  bf16* vTb = (bf16*)alloc((size_t)S_LEN * DMODEL * 2);
  bf16* aob = (bf16*)alloc((size_t)S_LEN * DMODEL * 2);
  bf16* midb = (bf16*)alloc((size_t)S_LEN * FFDIM * 2);

  for (int ly = 0; ly < NLAYER; ++ly) {
    k_tcast<<<dim3(3 * DMODEL / 32, DMODEL / 32), 256, 0, stream>>>(
        wqkv + (size_t)ly * DMODEL * 3 * DMODEL, wqkvT + (size_t)ly * 3 * DMODEL * DMODEL, DMODEL, 3 * DMODEL);
    k_tcast<<<dim3(DMODEL / 32, DMODEL / 32), 256, 0, stream>>>(
        wo + (size_t)ly * DMODEL * DMODEL, woT + (size_t)ly * DMODEL * DMODEL, DMODEL, DMODEL);
    k_tcast<<<dim3(FFDIM / 32, DMODEL / 32), 256, 0, stream>>>(
        wu + (size_t)ly * DMODEL * FFDIM, wuT + (size_t)ly * DMODEL * FFDIM, DMODEL, FFDIM);
    k_tcast<<<dim3(DMODEL / 32, FFDIM / 32), 256, 0, stream>>>(
        wd + (size_t)ly * FFDIM * DMODEL, wdT + (size_t)ly * FFDIM * DMODEL, FFDIM, DMODEL);
  }
  hipMemcpyAsync(hbuf, x, (size_t)S_LEN * DMODEL * 4, hipMemcpyDeviceToDevice, stream);

  for (int ly = 0; ly < NLAYER; ++ly) {
    k_ln<bf16><<<S_LEN, 256, 0, stream>>>(hbuf, ln0g + ly * DMODEL, ln0b + ly * DMODEL, ybuf);
    k_gemm_bt<0, 128><<<dim3(S_LEN / 128, 3 * DMODEL / 128), 256, 0, stream>>>(
        ybuf, wqkvT + (size_t)ly * 3 * DMODEL * DMODEL, bqkv + ly * 3 * DMODEL, nullptr, qkv,
        S_LEN, 3 * DMODEL, DMODEL);
    k_rope<<<S_LEN * NHEAD * 32 / 256, 256, 0, stream>>>(qkv, fcos, fsin, qrb, krb);
    k_tv<<<dim3(S_LEN / 64, NHEAD), 256, 0, stream>>>(qkv, vTb);
    k_attn<<<dim3(NHEAD, S_LEN / 16), 256, 0, stream>>>(qrb, krb, vTb, offs, aob);
    k_gemm_bt<1, 64><<<dim3(S_LEN / 64, DMODEL / 128), 256, 0, stream>>>(
        aob, woT + (size_t)ly * DMODEL * DMODEL, bo + ly * DMODEL, hbuf, hbuf,
        S_LEN, DMODEL, DMODEL);
    k_ln<bf16><<<S_LEN, 256, 0, stream>>>(hbuf, ln1g + ly * DMODEL, ln1b + ly * DMODEL, ybuf);
    k_gemm_bt<2, 128><<<dim3(S_LEN / 128, FFDIM / 128), 256, 0, stream>>>(
        ybuf, wuT + (size_t)ly * DMODEL * FFDIM, bu + ly * FFDIM, nullptr, midb,
        S_LEN, FFDIM, DMODEL);
    k_gemm_bt<1, 64><<<dim3(S_LEN / 64, DMODEL / 128), 256, 0, stream>>>(
        midb, wdT + (size_t)ly * FFDIM * DMODEL, bd + ly * DMODEL, hbuf, hbuf,
        S_LEN, DMODEL, FFDIM);
  }
  k_ln<float><<<S_LEN, 256, 0, stream>>>(hbuf, lnfg, lnfb, (float*)d_out);
}